// Round 3
// baseline (266.652 us; speedup 1.0000x reference)
//
#include <hip/hip_runtime.h>

// B=16, L=2048, V=64.
// Algebraic reduction (e is one-hot):
//   E[d] = exp(v_emb[d]); S[t] = prefix_sum(E)[t]
//   F[b,c,s] = sum_{k<=s} E[s-k] * Wq[idx[b,k], c]            (causal Toeplitz GEMM)
//   P[b,c,s] = exp(F[b,c,s] / S[s])                           (softmax w/o max; scores tiny)
//   out[b,t,v] = Wv00 * (sum_{s<=t, idx[b,s]==v} P[b,c_t,s]) / (sum_{s<=t} P[b,c_t,s]),  c_t = idx[b,t]
//
// R17: R16's fused kernel measured 180us with MfmaUtil=0.93%, VALUBusy=3.5%
// -> ~10-15us of real work, ~165us idle inside cg::this_grid().sync()
// (~80us/sync: ROCm cg grid-sync uses coarse sleep backoff + multigrid
// fencing). This round: SAME verified phase code + cooperative launch (for
// the co-residency guarantee), but hand-rolled device-scope atomic barriers
// (release fence + 1 atomic arrive per block + acquire spin w/ s_sleep(2)).
// Barrier counters in ws at +16MB, zeroed by a 256B hipMemsetAsync
// (graph-capture legal). Predicted: k_fused 180 -> 30-45us, total -> ~100us.

#define LSEQ 2048
#define NB 16
#define NV 64
#define NC 32             // 32 chunks of 64
#define NBLK 512          // fused grid size

typedef __attribute__((ext_vector_type(8))) short bf16x8;
typedef __attribute__((ext_vector_type(4))) float f32x4;

__device__ __forceinline__ unsigned short f2bf(float f) {   // RNE float->bf16
  unsigned int u = __float_as_uint(f);
  return (unsigned short)((u + 0x7FFFu + ((u >> 16) & 1u)) >> 16);
}

// Hand-rolled grid barrier: counter pre-zeroed by host-side memset.
// Mirrors ROCm cg's mechanism (release fence; atomic arrive; acquire spin)
// with fine-grained s_sleep. One atomic per block.
__device__ __forceinline__ void gridbar(unsigned int* cnt) {
  __syncthreads();                      // all block work done, all threads here
  if (threadIdx.x == 0) {
    __threadfence();                    // release: our global writes visible
    __hip_atomic_fetch_add(cnt, 1u, __ATOMIC_RELEASE, __HIP_MEMORY_SCOPE_AGENT);
    while (__hip_atomic_load(cnt, __ATOMIC_ACQUIRE, __HIP_MEMORY_SCOPE_AGENT) < NBLK)
      __builtin_amdgcn_s_sleep(2);      // ~128-cycle poll granularity
  }
  __syncthreads();                      // block released after tid0's acquire
}

// =====================================================================
// Fused kernel: phase0 gather+prep | bar | phase1 GEMM | bar | phase2
// scan+emit. Phase logic identical to R16 (correctness-verified).
// =====================================================================
__global__ __launch_bounds__(256, 2) void k_fused(
    const int* __restrict__ idx, const float* __restrict__ Wq,
    const float* __restrict__ Wv, const float* __restrict__ v_emb,
    unsigned short* __restrict__ Agr, unsigned short* __restrict__ Ebf,
    float* __restrict__ S, float* __restrict__ P, float* __restrict__ out,
    unsigned int* __restrict__ bar) {
  union SMem {
    struct {  // phase 1 (GEMM)
      unsigned short GL0[2208];   // GL0[i] = (127<=i<2175) ? E[i-127] : 0
      unsigned short GL1[2176];   // GL1[i] = GLv(i+1)
      float red[16][64];
      float red2[16][64];
    } g;
    struct {  // phase 2 (scan+emit)
      float Hs[NC][65];
      float bins[4][64];
    } s;
  };
  __shared__ SMem sm;

  const int bid = blockIdx.x;     // [0, 512)
  const int tid = threadIdx.x;
  const int w = tid >> 6;
  const int lane = tid & 63;

  // ---------------- phase 0: prep (1 wave) + gather -------------------
  {
    const int b = bid >> 5;
    const int sub = bid & 31;

    if (bid == 0 && tid < 64) {   // fused prep (one wave)
      const int base = lane * 32;
      float e[32];
      float run = 0.f;
#pragma unroll
      for (int i = 0; i < 32; ++i) { e[i] = expf(v_emb[base + i]); run += e[i]; }
      float incl = run;
#pragma unroll
      for (int d = 1; d < 64; d <<= 1) {
        float up = __shfl_up(incl, d);
        if (lane >= d) incl += up;
      }
      float acc = incl - run;
#pragma unroll
      for (int i = 0; i < 32; ++i) {
        acc += e[i];
        Ebf[base + i] = f2bf(e[i]);
        S[base + i] = acc;
      }
    }

    const int k8base = sub * 8 + w * 2;      // this wave's 2 k8-groups
#pragma unroll
    for (int r = 0; r < 2; ++r) {
      const int k8 = k8base + r;
      unsigned short v[8];
#pragma unroll
      for (int j = 0; j < 8; ++j) {
        const int ii = idx[b * LSEQ + (2047 - (k8 * 8 + j))];  // wave-uniform
        v[j] = f2bf(Wq[ii * 64 + lane]);                       // coalesced row read
      }
      uint4 st;
      st.x = (unsigned int)v[0] | ((unsigned int)v[1] << 16);
      st.y = (unsigned int)v[2] | ((unsigned int)v[3] << 16);
      st.z = (unsigned int)v[4] | ((unsigned int)v[5] << 16);
      st.w = (unsigned int)v[6] | ((unsigned int)v[7] << 16);
      *(uint4*)(Agr + ((size_t)(b * 256 + k8) * 64 + lane) * 8) = st;
    }
  }
  gridbar(bar + 0);

  // ---------------- phase 1: MFMA GEMM, two paired tiles --------------
  {
    const int b = bid >> 5;
    const int jj = bid & 31;                 // pair (bn=63-jj heavy, bn=jj light)
    const int quad = lane >> 4;
    const int lm = lane & 15;
    const int nsub = w & 1;                  // n-offset 0 / 16
    const int kh = w >> 1;                   // k-half 0 / 1
    const unsigned short* __restrict__ abase = Agr + (size_t)b * 256 * 64 * 8;

    // stage the window for the HEAVY tile (superset of the light tile's)
    {
      const int wend = (63 - jj) * 32 + 160;
      for (int i = 96 + tid; i < wend; i += 256) {
        const int e0 = i - 127;
        const int e1 = i - 126;
        sm.g.GL0[i] = (e0 >= 0 && e0 < LSEQ) ? Ebf[e0] : (unsigned short)0;
        sm.g.GL1[i] = (e1 >= 0 && e1 < LSEQ) ? Ebf[e1] : (unsigned short)0;
      }
    }
    __syncthreads();

    for (int half = 0; half < 2; ++half) {
      const int bn = half ? jj : (63 - jj);
      const int n0 = bn * 32;
      const int nbase = n0 + nsub * 16;
      const int sbase = nbase + lm - 1920;
      const int kstart = 2048 - (n0 + 32);   // multiple of 32
      const int iters = bn + 1;              // total 32-k steps for this tile

      f32x4 acc[4];
#pragma unroll
      for (int mt = 0; mt < 4; ++mt) acc[mt] = (f32x4){0.f, 0.f, 0.f, 0.f};

      union AF { uint4 u; bf16x8 v; };
      union BF { unsigned int u[4]; bf16x8 v; };
      AF a[3][4];
      BF bb[3];

#define LOAD_FRAGS(J_, SL) do {                                             \
    const int k_ = kstart + (kh + 2 * (J_)) * 32;                           \
    const int kq8_ = (k_ >> 3) + quad;                                      \
    const unsigned short* ab_ = abase + ((size_t)kq8_ * 64 + lm) * 8;       \
    a[SL][0].u = *(const uint4*)(ab_ + 0 * 128);                            \
    a[SL][1].u = *(const uint4*)(ab_ + 1 * 128);                            \
    a[SL][2].u = *(const uint4*)(ab_ + 2 * 128);                            \
    a[SL][3].u = *(const uint4*)(ab_ + 3 * 128);                            \
    const int s_ = sbase + k_ + quad * 8;                                   \
    const unsigned int* gb_ = (s_ & 1) ? (const unsigned int*)sm.g.GL1      \
                                       : (const unsigned int*)sm.g.GL0;     \
    const int off_ = s_ >> 1;                                               \
    bb[SL].u[0] = gb_[off_ + 0]; bb[SL].u[1] = gb_[off_ + 1];               \
    bb[SL].u[2] = gb_[off_ + 2]; bb[SL].u[3] = gb_[off_ + 3];               \
  } while (0)

#define MFMA4(SL) do {                                                      \
    acc[0] = __builtin_amdgcn_mfma_f32_16x16x32_bf16(a[SL][0].v, bb[SL].v, acc[0], 0, 0, 0); \
    acc[1] = __builtin_amdgcn_mfma_f32_16x16x32_bf16(a[SL][1].v, bb[SL].v, acc[1], 0, 0, 0); \
    acc[2] = __builtin_amdgcn_mfma_f32_16x16x32_bf16(a[SL][2].v, bb[SL].v, acc[2], 0, 0, 0); \
    acc[3] = __builtin_amdgcn_mfma_f32_16x16x32_bf16(a[SL][3].v, bb[SL].v, acc[3], 0, 0, 0); \
  } while (0)

      const int J = (iters > kh) ? ((iters - kh + 1) >> 1) : 0;  // wave-iters
      if (J > 0) {
        LOAD_FRAGS(0, 0);
        if (J > 1) LOAD_FRAGS(1, 1);
        int j = 0;
        while (true) {
          if (j + 2 < J) LOAD_FRAGS(j + 2, 2);
          MFMA4(0);
          if (++j >= J) break;
          if (j + 2 < J) LOAD_FRAGS(j + 2, 0);
          MFMA4(1);
          if (++j >= J) break;
          if (j + 2 < J) LOAD_FRAGS(j + 2, 1);
          MFMA4(2);
          if (++j >= J) break;
        }
      }
#undef LOAD_FRAGS
#undef MFMA4

      // reduce k-half 1 into k-half 0 via LDS
      if (kh == 1) {
        float (*rd)[64] = nsub ? sm.g.red2 : sm.g.red;
#pragma unroll
        for (int mt = 0; mt < 4; ++mt)
#pragma unroll
          for (int r = 0; r < 4; ++r) rd[mt * 4 + r][lane] = acc[mt][r];
      }
      __syncthreads();
      if (kh == 0) {
        float (*rd)[64] = nsub ? sm.g.red2 : sm.g.red;
#pragma unroll
        for (int mt = 0; mt < 4; ++mt)
#pragma unroll
          for (int r = 0; r < 4; ++r) acc[mt][r] += rd[mt * 4 + r][lane];

        // epilogue: C/D layout col(s)=lm, row(c)=quad*4+r
        const float sinv = 1.0f / S[nbase + lm];
#pragma unroll
        for (int mt = 0; mt < 4; ++mt) {
#pragma unroll
          for (int r = 0; r < 4; ++r) {
            const int c = mt * 16 + quad * 4 + r;
            P[((size_t)(b * 64 + c)) * LSEQ + nbase + lm] = __expf(acc[mt][r] * sinv);
          }
        }
      }
      __syncthreads();   // protect red/red2 reuse by the second tile
    }
  }
  gridbar(bar + 32);     // second counter, 128B away from the first

  // ---------------- phase 2: chunk-hists + scan + emission ------------
  {
    for (int q = 0; q < 2; ++q) {
      const int bc = (bid << 1) | q;   // [0, 1024)
      const int b2 = bc >> 6;
      const int c = bc & 63;
      const float* __restrict__ prow = P + (size_t)bc * LSEQ;
      const int* __restrict__ irow = idx + b2 * LSEQ;

      float p[8]; int ii[8];
#pragma unroll
      for (int r = 0; r < 8; ++r) {
        const int ch = w * 8 + r;
        p[r] = prow[ch * 64 + lane];
        ii[r] = irow[ch * 64 + lane];
      }
      __syncthreads();               // protect Hs from prior-iter readers
      for (int i = tid; i < NC * 65; i += 256) ((float*)sm.s.Hs)[i] = 0.f;
      __syncthreads();
#pragma unroll
      for (int r = 0; r < 8; ++r) atomicAdd(&sm.s.Hs[w * 8 + r][ii[r]], p[r]);
      __syncthreads();

      // exclusive scan across chunks, per bin: 2 bins per pass
      const int hhalf = lane >> 5, l32 = lane & 31;
#pragma unroll
      for (int r = 0; r < 8; ++r) {
        const int v = w * 16 + r * 2 + hhalf;
        const float h = sm.s.Hs[l32][v];
        float x = h;
#pragma unroll
        for (int d = 1; d < 32; d <<= 1) {
          float up = __shfl_up(x, d, 32);
          if (l32 >= d) x += up;
        }
        sm.s.Hs[l32][v] = x - h;     // exclusive
      }
      __syncthreads();

      const float wv = Wv[0];
#pragma unroll
      for (int r = 0; r < 8; ++r) {
        const int ch = w * 8 + r;
        unsigned long long m = __ballot(ii[r] == c);
        while (m) {
          const int srel = __builtin_ctzll(m);
          m &= m - 1;
          const int t = ch * 64 + srel;
          const float pm = (lane <= srel) ? p[r] : 0.f;
          sm.s.bins[w][lane] = 0.f;
          __threadfence_block();
          atomicAdd(&sm.s.bins[w][ii[r]], pm);
          __threadfence_block();
          const float bin = sm.s.bins[w][lane] + sm.s.Hs[ch][lane];
          float z = bin;
#pragma unroll
          for (int d = 1; d < 64; d <<= 1) z += __shfl_xor(z, d);
          out[((size_t)(b2 * LSEQ + t)) * 64 + lane] = wv * bin / z;
        }
      }
    }
  }
}

// =====================================================================
// Fallback path: the verified 3-kernel pipeline (R11), used only if the
// cooperative launch is rejected.
// =====================================================================
__global__ __launch_bounds__(256) void k_gather(const int* __restrict__ idx,
                                                const float* __restrict__ Wq,
                                                const float* __restrict__ v_emb,
                                                unsigned short* __restrict__ Agr,
                                                unsigned short* __restrict__ Ebf,
                                                float* __restrict__ S) {
  const int b = blockIdx.x >> 4;
  const int tile = blockIdx.x & 15;
  const int w = threadIdx.x >> 6;
  const int lane = threadIdx.x & 63;

  if (blockIdx.x == 0 && threadIdx.x < 64) {
    const int base = lane * 32;
    float e[32];
    float run = 0.f;
#pragma unroll
    for (int i = 0; i < 32; ++i) { e[i] = expf(v_emb[base + i]); run += e[i]; }
    float incl = run;
#pragma unroll
    for (int d = 1; d < 64; d <<= 1) {
      float up = __shfl_up(incl, d);
      if (lane >= d) incl += up;
    }
    float acc = incl - run;
#pragma unroll
    for (int i = 0; i < 32; ++i) {
      acc += e[i];
      Ebf[base + i] = f2bf(e[i]);
      S[base + i] = acc;
    }
  }

  const int k8base = tile * 16 + w * 4;
#pragma unroll
  for (int r = 0; r < 4; ++r) {
    const int k8 = k8base + r;
    unsigned short v[8];
#pragma unroll
    for (int j = 0; j < 8; ++j) {
      const int ii = idx[b * LSEQ + (2047 - (k8 * 8 + j))];
      v[j] = f2bf(Wq[ii * 64 + lane]);
    }
    uint4 st;
    st.x = (unsigned int)v[0] | ((unsigned int)v[1] << 16);
    st.y = (unsigned int)v[2] | ((unsigned int)v[3] << 16);
    st.z = (unsigned int)v[4] | ((unsigned int)v[5] << 16);
    st.w = (unsigned int)v[6] | ((unsigned int)v[7] << 16);
    *(uint4*)(Agr + ((size_t)(b * 256 + k8) * 64 + lane) * 8) = st;
  }
}

__global__ __launch_bounds__(256) void k_gemm(const unsigned short* __restrict__ Agr,
                                              const unsigned short* __restrict__ Ebf,
                                              const float* __restrict__ S,
                                              float* __restrict__ P) {
  __shared__ unsigned short GL0[2208];
  __shared__ unsigned short GL1[2176];
  __shared__ float red[16][64];
  __shared__ float red2[16][64];

  const int b  = blockIdx.y;
  const int bn = 63 - (int)blockIdx.x;
  const int n0 = bn * 32;
  const int tid = threadIdx.x;
  const int w = tid >> 6;
  const int lane = tid & 63;
  const int quad = lane >> 4;
  const int lm = lane & 15;
  const int nsub = w & 1;
  const int kh = w >> 1;

  {
    const int wend = n0 + 160;
    for (int i = 96 + tid; i < wend; i += 256) {
      const int e0 = i - 127;
      const int e1 = i - 126;
      GL0[i] = (e0 >= 0 && e0 < LSEQ) ? Ebf[e0] : (unsigned short)0;
      GL1[i] = (e1 >= 0 && e1 < LSEQ) ? Ebf[e1] : (unsigned short)0;
    }
  }
  __syncthreads();

  f32x4 acc[4];
#pragma unroll
  for (int mt = 0; mt < 4; ++mt) acc[mt] = (f32x4){0.f, 0.f, 0.f, 0.f};

  const int nbase = n0 + nsub * 16;
  const int sbase = nbase + lm - 1920;
  const int kstart = 2048 - (n0 + 32);
  const int iters = bn + 1;
  const unsigned short* __restrict__ abase = Agr + (size_t)b * 256 * 64 * 8;

  union AF { uint4 u; bf16x8 v; };
  union BF { unsigned int u[4]; bf16x8 v; };
  AF a[3][4];
  BF bb[3];

#define LOAD_FRAGS(J_, SL) do {                                             \
    const int k_ = kstart + (kh + 2 * (J_)) * 32;                           \
    const int kq8_ = (k_ >> 3) + quad;                                      \
    const unsigned short* ab_ = abase + ((size_t)kq8_ * 64 + lm) * 8;       \
    a[SL][0].u = *(const uint4*)(ab_ + 0 * 128);                            \
    a[SL][1].u = *(const uint4*)(ab_ + 1 * 128);                            \
    a[SL][2].u = *(const uint4*)(ab_ + 2 * 128);                            \
    a[SL][3].u = *(const uint4*)(ab_ + 3 * 128);                            \
    const int s_ = sbase + k_ + quad * 8;                                   \
    const unsigned int* gb_ = (s_ & 1) ? (const unsigned int*)GL1           \
                                       : (const unsigned int*)GL0;          \
    const int off_ = s_ >> 1;                                               \
    bb[SL].u[0] = gb_[off_ + 0]; bb[SL].u[1] = gb_[off_ + 1];               \
    bb[SL].u[2] = gb_[off_ + 2]; bb[SL].u[3] = gb_[off_ + 3];               \
  } while (0)

#define MFMA4(SL) do {                                                      \
    acc[0] = __builtin_amdgcn_mfma_f32_16x16x32_bf16(a[SL][0].v, bb[SL].v, acc[0], 0, 0, 0); \
    acc[1] = __builtin_amdgcn_mfma_f32_16x16x32_bf16(a[SL][1].v, bb[SL].v, acc[1], 0, 0, 0); \
    acc[2] = __builtin_amdgcn_mfma_f32_16x16x32_bf16(a[SL][2].v, bb[SL].v, acc[2], 0, 0, 0); \
    acc[3] = __builtin_amdgcn_mfma_f32_16x16x32_bf16(a[SL][3].v, bb[SL].v, acc[3], 0, 0, 0); \
  } while (0)

  const int J = (iters > kh) ? ((iters - kh + 1) >> 1) : 0;
  if (J > 0) {
    LOAD_FRAGS(0, 0);
    if (J > 1) LOAD_FRAGS(1, 1);
    int j = 0;
    while (true) {
      if (j + 2 < J) LOAD_FRAGS(j + 2, 2);
      MFMA4(0);
      if (++j >= J) break;
      if (j + 2 < J) LOAD_FRAGS(j + 2, 0);
      MFMA4(1);
      if (++j >= J) break;
      if (j + 2 < J) LOAD_FRAGS(j + 2, 1);
      MFMA4(2);
      if (++j >= J) break;
    }
  }
#undef LOAD_FRAGS
#undef MFMA4

  if (kh == 1) {
    float (*rd)[64] = nsub ? red2 : red;
#pragma unroll
    for (int mt = 0; mt < 4; ++mt)
#pragma unroll
      for (int r = 0; r < 4; ++r) rd[mt * 4 + r][lane] = acc[mt][r];
  }
  __syncthreads();
  if (kh == 0) {
    float (*rd)[64] = nsub ? red2 : red;
#pragma unroll
    for (int mt = 0; mt < 4; ++mt)
#pragma unroll
      for (int r = 0; r < 4; ++r) acc[mt][r] += rd[mt * 4 + r][lane];

    const float sinv = 1.0f / S[nbase + lm];
#pragma unroll
    for (int mt = 0; mt < 4; ++mt) {
#pragma unroll
      for (int r = 0; r < 4; ++r) {
        const int c = mt * 16 + quad * 4 + r;
        P[((size_t)(b * 64 + c)) * LSEQ + nbase + lm] = __expf(acc[mt][r] * sinv);
      }
    }
  }
}

__global__ __launch_bounds__(256) void k_scanemit(const int* __restrict__ idx,
                                                  const float* __restrict__ P,
                                                  const float* __restrict__ Wv,
                                                  float* __restrict__ out) {
  __shared__ float Hs[NC][65];
  __shared__ float bins[4][64];
  const int bc = blockIdx.x;
  const int b = bc >> 6;
  const int c = bc & 63;
  const int w = threadIdx.x >> 6;
  const int lane = threadIdx.x & 63;

  const float* __restrict__ prow = P + (size_t)bc * LSEQ;
  const int* __restrict__ irow = idx + b * LSEQ;

  float p[8]; int ii[8];
#pragma unroll
  for (int r = 0; r < 8; ++r) {
    const int ch = w * 8 + r;
    p[r] = prow[ch * 64 + lane];
    ii[r] = irow[ch * 64 + lane];
  }
  for (int i = threadIdx.x; i < NC * 65; i += 256) ((float*)Hs)[i] = 0.f;
  __syncthreads();
#pragma unroll
  for (int r = 0; r < 8; ++r) atomicAdd(&Hs[w * 8 + r][ii[r]], p[r]);
  __syncthreads();

  const int half = lane >> 5, l32 = lane & 31;
#pragma unroll
  for (int r = 0; r < 8; ++r) {
    const int v = w * 16 + r * 2 + half;
    const float h = Hs[l32][v];
    float x = h;
#pragma unroll
    for (int d = 1; d < 32; d <<= 1) {
      float up = __shfl_up(x, d, 32);
      if (l32 >= d) x += up;
    }
    Hs[l32][v] = x - h;
  }
  __syncthreads();

  const float wv = Wv[0];
#pragma unroll
  for (int r = 0; r < 8; ++r) {
    const int ch = w * 8 + r;
    unsigned long long m = __ballot(ii[r] == c);
    while (m) {
      const int srel = __builtin_ctzll(m);
      m &= m - 1;
      const int t = ch * 64 + srel;
      const float pm = (lane <= srel) ? p[r] : 0.f;
      bins[w][lane] = 0.f;
      __threadfence_block();
      atomicAdd(&bins[w][ii[r]], pm);
      __threadfence_block();
      const float bin = bins[w][lane] + Hs[ch][lane];
      float z = bin;
#pragma unroll
      for (int d = 1; d < 64; d <<= 1) z += __shfl_xor(z, d);
      out[((size_t)(b * LSEQ + t)) * 64 + lane] = wv * bin / z;
    }
  }
}

extern "C" void kernel_launch(void* const* d_in, const int* in_sizes, int n_in,
                              void* d_out, int out_size, void* d_ws, size_t ws_size,
                              hipStream_t stream) {
  const int* idx     = (const int*)d_in[0];     // [16, 2048]
  const float* Wq    = (const float*)d_in[1];   // [64, 64]
  const float* Wv    = (const float*)d_in[2];   // [64, 64] (only [0,0] used)
  const float* v_emb = (const float*)d_in[3];   // [2048, 1]
  float* out = (float*)d_out;                   // [16, 2048, 64] fp32

  // workspace: S[2048] f32 | P[1024*2048] f32 | Ebf[2048] bf16 | Agr[16*256*64*8] bf16
  // barrier counters at +16MB (past the ~12.6MB data footprint)
  float* S = (float*)d_ws;
  float* P = S + LSEQ;
  unsigned short* Ebf = (unsigned short*)(P + (size_t)NB * NV * LSEQ);
  unsigned short* Agr = Ebf + LSEQ;
  unsigned int* bar = (unsigned int*)((char*)d_ws + (16u << 20));

  hipMemsetAsync(bar, 0, 256, stream);   // zero both barrier counters

  const int* a_idx = idx; const float* a_Wq = Wq; const float* a_Wv = Wv;
  const float* a_vemb = v_emb;
  unsigned short* a_Agr = Agr; unsigned short* a_Ebf = Ebf;
  float* a_S = S; float* a_P = P; float* a_out = out;
  unsigned int* a_bar = bar;
  void* args[] = {(void*)&a_idx, (void*)&a_Wq, (void*)&a_Wv, (void*)&a_vemb,
                  (void*)&a_Agr, (void*)&a_Ebf, (void*)&a_S, (void*)&a_P,
                  (void*)&a_out, (void*)&a_bar};

  hipError_t cerr = hipLaunchCooperativeKernel((void*)k_fused, dim3(NBLK),
                                               dim3(256), args, 0, stream);
  if (cerr != hipSuccess) {
    (void)hipGetLastError();   // clear sticky error, fall back to 3-kernel path
    k_gather<<<NB * 16, 256, 0, stream>>>(idx, Wq, v_emb, Agr, Ebf, S);
    k_gemm<<<dim3(64, NB), 256, 0, stream>>>(Agr, Ebf, S, P);
    k_scanemit<<<NB * NV, 256, 0, stream>>>(idx, P, Wv, out);
  }
}

// Round 4
// 175.543 us; speedup vs baseline: 1.5190x; 1.5190x over previous
//
#include <hip/hip_runtime.h>

// B=16, L=2048, V=64.
// Algebraic reduction (e is one-hot):
//   E[d] = exp(v_emb[d]); S[t] = prefix_sum(E)[t]
//   F[b,c,s] = sum_{k<=s} E[s-k] * Wq[idx[b,k], c]            (causal Toeplitz GEMM)
//   P[b,c,s] = exp(F[b,c,s] / S[s])                           (softmax w/o max; scores tiny)
//   out[b,t,v] = Wv00 * (sum_{s<=t, idx[b,s]==v} P[b,c_t,s]) / (sum_{s<=t} P[b,c_t,s]),  c_t = idx[b,t]
//
// R19: R17's counter-spin barrier = 191us (same as cg's 180) -> the MECHANISM
// is the cost: 511 acquire-polls/block on the SAME line as 512 RMW arrivals
// serialize at one L2 bank (~90us/sync), and each acquire poll invalidates
// L1/L2. This round: arrive = 1 release fetch_add (nobody polls it); LAST
// arriver (old==NBLK-1) becomes leader and writes 512 per-block mailbox
// flags (128B-strided); waiters spin on OWN flag with RELAXED agent loads
// (line-granular, no cache-wide inv) + s_sleep(4), then ONE acquire fence.
// Separate flag arrays per barrier (else late leader-1 stores can overwrite
// leader-2 stores -> deadlock). Predicted k_fused 191 -> 25-50us.

#define LSEQ 2048
#define NB 16
#define NV 64
#define NC 32             // 32 chunks of 64
#define NBLK 512          // fused grid size

typedef __attribute__((ext_vector_type(8))) short bf16x8;
typedef __attribute__((ext_vector_type(4))) float f32x4;

__device__ __forceinline__ unsigned short f2bf(float f) {   // RNE float->bf16
  unsigned int u = __float_as_uint(f);
  return (unsigned short)((u + 0x7FFFu + ((u >> 16) & 1u)) >> 16);
}

// Mailbox grid barrier. cnt: arrival counter (pre-zeroed). flags: NBLK lines
// of 32 uints each (pre-zeroed); flag[bid*32] flips 0->1 exactly once.
__device__ __forceinline__ void gridbar(unsigned int* cnt, unsigned int* flags,
                                        unsigned int* s_leader) {
  __syncthreads();                      // all block work done
  if (threadIdx.x == 0) {
    unsigned int old = __hip_atomic_fetch_add(cnt, 1u, __ATOMIC_RELEASE,
                                              __HIP_MEMORY_SCOPE_AGENT);
    *s_leader = (old == NBLK - 1u) ? 1u : 0u;
  }
  __syncthreads();
  if (*s_leader) {                      // block-uniform branch
    __builtin_amdgcn_fence(__ATOMIC_ACQUIRE, "agent");
    __builtin_amdgcn_fence(__ATOMIC_RELEASE, "agent");
#pragma unroll
    for (int i = threadIdx.x; i < NBLK; i += 256)
      __hip_atomic_store(flags + (size_t)i * 32, 1u, __ATOMIC_RELAXED,
                         __HIP_MEMORY_SCOPE_AGENT);
    // leader block proceeds; its own flag value is irrelevant
  } else {
    if (threadIdx.x == 0) {
      while (__hip_atomic_load(flags + (size_t)blockIdx.x * 32,
                               __ATOMIC_RELAXED,
                               __HIP_MEMORY_SCOPE_AGENT) == 0u)
        __builtin_amdgcn_s_sleep(4);    // ~256-cycle poll, own line only
      __builtin_amdgcn_fence(__ATOMIC_ACQUIRE, "agent");
    }
    __syncthreads();
  }
}

// =====================================================================
// Fused kernel: phase0 gather+prep | bar | phase1 GEMM | bar | phase2
// scan+emit. Phase logic identical to R16/R17 (correctness-verified).
// =====================================================================
__global__ __launch_bounds__(256, 2) void k_fused(
    const int* __restrict__ idx, const float* __restrict__ Wq,
    const float* __restrict__ Wv, const float* __restrict__ v_emb,
    unsigned short* __restrict__ Agr, unsigned short* __restrict__ Ebf,
    float* __restrict__ S, float* __restrict__ P, float* __restrict__ out,
    unsigned int* __restrict__ bar) {
  union SMem {
    struct {  // phase 1 (GEMM)
      unsigned short GL0[2208];   // GL0[i] = (127<=i<2175) ? E[i-127] : 0
      unsigned short GL1[2176];   // GL1[i] = GLv(i+1)
      float red[16][64];
      float red2[16][64];
    } g;
    struct {  // phase 2 (scan+emit)
      float Hs[NC][65];
      float bins[4][64];
    } s;
  };
  __shared__ SMem sm;
  __shared__ unsigned int s_leader;

  // barrier memory layout inside bar: cnt1 @ +0, cnt2 @ +32 (uints),
  // flags1 @ +1024, flags2 @ +1024+16384 (uints)
  unsigned int* cnt1 = bar;
  unsigned int* cnt2 = bar + 32;
  unsigned int* flags1 = bar + 1024;
  unsigned int* flags2 = bar + 1024 + 16384;

  const int bid = blockIdx.x;     // [0, 512)
  const int tid = threadIdx.x;
  const int w = tid >> 6;
  const int lane = tid & 63;

  // ---------------- phase 0: prep (1 wave) + gather -------------------
  {
    const int b = bid >> 5;
    const int sub = bid & 31;

    if (bid == 0 && tid < 64) {   // fused prep (one wave)
      const int base = lane * 32;
      float e[32];
      float run = 0.f;
#pragma unroll
      for (int i = 0; i < 32; ++i) { e[i] = expf(v_emb[base + i]); run += e[i]; }
      float incl = run;
#pragma unroll
      for (int d = 1; d < 64; d <<= 1) {
        float up = __shfl_up(incl, d);
        if (lane >= d) incl += up;
      }
      float acc = incl - run;
#pragma unroll
      for (int i = 0; i < 32; ++i) {
        acc += e[i];
        Ebf[base + i] = f2bf(e[i]);
        S[base + i] = acc;
      }
    }

    const int k8base = sub * 8 + w * 2;      // this wave's 2 k8-groups
#pragma unroll
    for (int r = 0; r < 2; ++r) {
      const int k8 = k8base + r;
      unsigned short v[8];
#pragma unroll
      for (int j = 0; j < 8; ++j) {
        const int ii = idx[b * LSEQ + (2047 - (k8 * 8 + j))];  // wave-uniform
        v[j] = f2bf(Wq[ii * 64 + lane]);                       // coalesced row read
      }
      uint4 st;
      st.x = (unsigned int)v[0] | ((unsigned int)v[1] << 16);
      st.y = (unsigned int)v[2] | ((unsigned int)v[3] << 16);
      st.z = (unsigned int)v[4] | ((unsigned int)v[5] << 16);
      st.w = (unsigned int)v[6] | ((unsigned int)v[7] << 16);
      *(uint4*)(Agr + ((size_t)(b * 256 + k8) * 64 + lane) * 8) = st;
    }
  }
  gridbar(cnt1, flags1, &s_leader);

  // ---------------- phase 1: MFMA GEMM, two paired tiles --------------
  {
    const int b = bid >> 5;
    const int jj = bid & 31;                 // pair (bn=63-jj heavy, bn=jj light)
    const int quad = lane >> 4;
    const int lm = lane & 15;
    const int nsub = w & 1;                  // n-offset 0 / 16
    const int kh = w >> 1;                   // k-half 0 / 1
    const unsigned short* __restrict__ abase = Agr + (size_t)b * 256 * 64 * 8;

    // stage the window for the HEAVY tile (superset of the light tile's)
    {
      const int wend = (63 - jj) * 32 + 160;
      for (int i = 96 + tid; i < wend; i += 256) {
        const int e0 = i - 127;
        const int e1 = i - 126;
        sm.g.GL0[i] = (e0 >= 0 && e0 < LSEQ) ? Ebf[e0] : (unsigned short)0;
        sm.g.GL1[i] = (e1 >= 0 && e1 < LSEQ) ? Ebf[e1] : (unsigned short)0;
      }
    }
    __syncthreads();

    for (int half = 0; half < 2; ++half) {
      const int bn = half ? jj : (63 - jj);
      const int n0 = bn * 32;
      const int nbase = n0 + nsub * 16;
      const int sbase = nbase + lm - 1920;
      const int kstart = 2048 - (n0 + 32);   // multiple of 32
      const int iters = bn + 1;              // total 32-k steps for this tile

      f32x4 acc[4];
#pragma unroll
      for (int mt = 0; mt < 4; ++mt) acc[mt] = (f32x4){0.f, 0.f, 0.f, 0.f};

      union AF { uint4 u; bf16x8 v; };
      union BF { unsigned int u[4]; bf16x8 v; };
      AF a[3][4];
      BF bb[3];

#define LOAD_FRAGS(J_, SL) do {                                             \
    const int k_ = kstart + (kh + 2 * (J_)) * 32;                           \
    const int kq8_ = (k_ >> 3) + quad;                                      \
    const unsigned short* ab_ = abase + ((size_t)kq8_ * 64 + lm) * 8;       \
    a[SL][0].u = *(const uint4*)(ab_ + 0 * 128);                            \
    a[SL][1].u = *(const uint4*)(ab_ + 1 * 128);                            \
    a[SL][2].u = *(const uint4*)(ab_ + 2 * 128);                            \
    a[SL][3].u = *(const uint4*)(ab_ + 3 * 128);                            \
    const int s_ = sbase + k_ + quad * 8;                                   \
    const unsigned int* gb_ = (s_ & 1) ? (const unsigned int*)sm.g.GL1      \
                                       : (const unsigned int*)sm.g.GL0;     \
    const int off_ = s_ >> 1;                                               \
    bb[SL].u[0] = gb_[off_ + 0]; bb[SL].u[1] = gb_[off_ + 1];               \
    bb[SL].u[2] = gb_[off_ + 2]; bb[SL].u[3] = gb_[off_ + 3];               \
  } while (0)

#define MFMA4(SL) do {                                                      \
    acc[0] = __builtin_amdgcn_mfma_f32_16x16x32_bf16(a[SL][0].v, bb[SL].v, acc[0], 0, 0, 0); \
    acc[1] = __builtin_amdgcn_mfma_f32_16x16x32_bf16(a[SL][1].v, bb[SL].v, acc[1], 0, 0, 0); \
    acc[2] = __builtin_amdgcn_mfma_f32_16x16x32_bf16(a[SL][2].v, bb[SL].v, acc[2], 0, 0, 0); \
    acc[3] = __builtin_amdgcn_mfma_f32_16x16x32_bf16(a[SL][3].v, bb[SL].v, acc[3], 0, 0, 0); \
  } while (0)

      const int J = (iters > kh) ? ((iters - kh + 1) >> 1) : 0;  // wave-iters
      if (J > 0) {
        LOAD_FRAGS(0, 0);
        if (J > 1) LOAD_FRAGS(1, 1);
        int j = 0;
        while (true) {
          if (j + 2 < J) LOAD_FRAGS(j + 2, 2);
          MFMA4(0);
          if (++j >= J) break;
          if (j + 2 < J) LOAD_FRAGS(j + 2, 0);
          MFMA4(1);
          if (++j >= J) break;
          if (j + 2 < J) LOAD_FRAGS(j + 2, 1);
          MFMA4(2);
          if (++j >= J) break;
        }
      }
#undef LOAD_FRAGS
#undef MFMA4

      // reduce k-half 1 into k-half 0 via LDS
      if (kh == 1) {
        float (*rd)[64] = nsub ? sm.g.red2 : sm.g.red;
#pragma unroll
        for (int mt = 0; mt < 4; ++mt)
#pragma unroll
          for (int r = 0; r < 4; ++r) rd[mt * 4 + r][lane] = acc[mt][r];
      }
      __syncthreads();
      if (kh == 0) {
        float (*rd)[64] = nsub ? sm.g.red2 : sm.g.red;
#pragma unroll
        for (int mt = 0; mt < 4; ++mt)
#pragma unroll
          for (int r = 0; r < 4; ++r) acc[mt][r] += rd[mt * 4 + r][lane];

        // epilogue: C/D layout col(s)=lm, row(c)=quad*4+r
        const float sinv = 1.0f / S[nbase + lm];
#pragma unroll
        for (int mt = 0; mt < 4; ++mt) {
#pragma unroll
          for (int r = 0; r < 4; ++r) {
            const int c = mt * 16 + quad * 4 + r;
            P[((size_t)(b * 64 + c)) * LSEQ + nbase + lm] = __expf(acc[mt][r] * sinv);
          }
        }
      }
      __syncthreads();   // protect red/red2 reuse by the second tile
    }
  }
  gridbar(cnt2, flags2, &s_leader);

  // ---------------- phase 2: chunk-hists + scan + emission ------------
  {
    for (int q = 0; q < 2; ++q) {
      const int bc = (bid << 1) | q;   // [0, 1024)
      const int b2 = bc >> 6;
      const int c = bc & 63;
      const float* __restrict__ prow = P + (size_t)bc * LSEQ;
      const int* __restrict__ irow = idx + b2 * LSEQ;

      float p[8]; int ii[8];
#pragma unroll
      for (int r = 0; r < 8; ++r) {
        const int ch = w * 8 + r;
        p[r] = prow[ch * 64 + lane];
        ii[r] = irow[ch * 64 + lane];
      }
      __syncthreads();               // protect Hs from prior-iter readers
      for (int i = tid; i < NC * 65; i += 256) ((float*)sm.s.Hs)[i] = 0.f;
      __syncthreads();
#pragma unroll
      for (int r = 0; r < 8; ++r) atomicAdd(&sm.s.Hs[w * 8 + r][ii[r]], p[r]);
      __syncthreads();

      // exclusive scan across chunks, per bin: 2 bins per pass
      const int hhalf = lane >> 5, l32 = lane & 31;
#pragma unroll
      for (int r = 0; r < 8; ++r) {
        const int v = w * 16 + r * 2 + hhalf;
        const float h = sm.s.Hs[l32][v];
        float x = h;
#pragma unroll
        for (int d = 1; d < 32; d <<= 1) {
          float up = __shfl_up(x, d, 32);
          if (l32 >= d) x += up;
        }
        sm.s.Hs[l32][v] = x - h;     // exclusive
      }
      __syncthreads();

      const float wv = Wv[0];
#pragma unroll
      for (int r = 0; r < 8; ++r) {
        const int ch = w * 8 + r;
        unsigned long long m = __ballot(ii[r] == c);
        while (m) {
          const int srel = __builtin_ctzll(m);
          m &= m - 1;
          const int t = ch * 64 + srel;
          const float pm = (lane <= srel) ? p[r] : 0.f;
          sm.s.bins[w][lane] = 0.f;
          __threadfence_block();
          atomicAdd(&sm.s.bins[w][ii[r]], pm);
          __threadfence_block();
          const float bin = sm.s.bins[w][lane] + sm.s.Hs[ch][lane];
          float z = bin;
#pragma unroll
          for (int d = 1; d < 64; d <<= 1) z += __shfl_xor(z, d);
          out[((size_t)(b2 * LSEQ + t)) * 64 + lane] = wv * bin / z;
        }
      }
    }
  }
}

// =====================================================================
// Fallback path: the verified 3-kernel pipeline (R11), used only if the
// cooperative launch is rejected.
// =====================================================================
__global__ __launch_bounds__(256) void k_gather(const int* __restrict__ idx,
                                                const float* __restrict__ Wq,
                                                const float* __restrict__ v_emb,
                                                unsigned short* __restrict__ Agr,
                                                unsigned short* __restrict__ Ebf,
                                                float* __restrict__ S) {
  const int b = blockIdx.x >> 4;
  const int tile = blockIdx.x & 15;
  const int w = threadIdx.x >> 6;
  const int lane = threadIdx.x & 63;

  if (blockIdx.x == 0 && threadIdx.x < 64) {
    const int base = lane * 32;
    float e[32];
    float run = 0.f;
#pragma unroll
    for (int i = 0; i < 32; ++i) { e[i] = expf(v_emb[base + i]); run += e[i]; }
    float incl = run;
#pragma unroll
    for (int d = 1; d < 64; d <<= 1) {
      float up = __shfl_up(incl, d);
      if (lane >= d) incl += up;
    }
    float acc = incl - run;
#pragma unroll
    for (int i = 0; i < 32; ++i) {
      acc += e[i];
      Ebf[base + i] = f2bf(e[i]);
      S[base + i] = acc;
    }
  }

  const int k8base = tile * 16 + w * 4;
#pragma unroll
  for (int r = 0; r < 4; ++r) {
    const int k8 = k8base + r;
    unsigned short v[8];
#pragma unroll
    for (int j = 0; j < 8; ++j) {
      const int ii = idx[b * LSEQ + (2047 - (k8 * 8 + j))];
      v[j] = f2bf(Wq[ii * 64 + lane]);
    }
    uint4 st;
    st.x = (unsigned int)v[0] | ((unsigned int)v[1] << 16);
    st.y = (unsigned int)v[2] | ((unsigned int)v[3] << 16);
    st.z = (unsigned int)v[4] | ((unsigned int)v[5] << 16);
    st.w = (unsigned int)v[6] | ((unsigned int)v[7] << 16);
    *(uint4*)(Agr + ((size_t)(b * 256 + k8) * 64 + lane) * 8) = st;
  }
}

__global__ __launch_bounds__(256) void k_gemm(const unsigned short* __restrict__ Agr,
                                              const unsigned short* __restrict__ Ebf,
                                              const float* __restrict__ S,
                                              float* __restrict__ P) {
  __shared__ unsigned short GL0[2208];
  __shared__ unsigned short GL1[2176];
  __shared__ float red[16][64];
  __shared__ float red2[16][64];

  const int b  = blockIdx.y;
  const int bn = 63 - (int)blockIdx.x;
  const int n0 = bn * 32;
  const int tid = threadIdx.x;
  const int w = tid >> 6;
  const int lane = tid & 63;
  const int quad = lane >> 4;
  const int lm = lane & 15;
  const int nsub = w & 1;
  const int kh = w >> 1;

  {
    const int wend = n0 + 160;
    for (int i = 96 + tid; i < wend; i += 256) {
      const int e0 = i - 127;
      const int e1 = i - 126;
      GL0[i] = (e0 >= 0 && e0 < LSEQ) ? Ebf[e0] : (unsigned short)0;
      GL1[i] = (e1 >= 0 && e1 < LSEQ) ? Ebf[e1] : (unsigned short)0;
    }
  }
  __syncthreads();

  f32x4 acc[4];
#pragma unroll
  for (int mt = 0; mt < 4; ++mt) acc[mt] = (f32x4){0.f, 0.f, 0.f, 0.f};

  const int nbase = n0 + nsub * 16;
  const int sbase = nbase + lm - 1920;
  const int kstart = 2048 - (n0 + 32);
  const int iters = bn + 1;
  const unsigned short* __restrict__ abase = Agr + (size_t)b * 256 * 64 * 8;

  union AF { uint4 u; bf16x8 v; };
  union BF { unsigned int u[4]; bf16x8 v; };
  AF a[3][4];
  BF bb[3];

#define LOAD_FRAGS(J_, SL) do {                                             \
    const int k_ = kstart + (kh + 2 * (J_)) * 32;                           \
    const int kq8_ = (k_ >> 3) + quad;                                      \
    const unsigned short* ab_ = abase + ((size_t)kq8_ * 64 + lm) * 8;       \
    a[SL][0].u = *(const uint4*)(ab_ + 0 * 128);                            \
    a[SL][1].u = *(const uint4*)(ab_ + 1 * 128);                            \
    a[SL][2].u = *(const uint4*)(ab_ + 2 * 128);                            \
    a[SL][3].u = *(const uint4*)(ab_ + 3 * 128);                            \
    const int s_ = sbase + k_ + quad * 8;                                   \
    const unsigned int* gb_ = (s_ & 1) ? (const unsigned int*)GL1           \
                                       : (const unsigned int*)GL0;          \
    const int off_ = s_ >> 1;                                               \
    bb[SL].u[0] = gb_[off_ + 0]; bb[SL].u[1] = gb_[off_ + 1];               \
    bb[SL].u[2] = gb_[off_ + 2]; bb[SL].u[3] = gb_[off_ + 3];               \
  } while (0)

#define MFMA4(SL) do {                                                      \
    acc[0] = __builtin_amdgcn_mfma_f32_16x16x32_bf16(a[SL][0].v, bb[SL].v, acc[0], 0, 0, 0); \
    acc[1] = __builtin_amdgcn_mfma_f32_16x16x32_bf16(a[SL][1].v, bb[SL].v, acc[1], 0, 0, 0); \
    acc[2] = __builtin_amdgcn_mfma_f32_16x16x32_bf16(a[SL][2].v, bb[SL].v, acc[2], 0, 0, 0); \
    acc[3] = __builtin_amdgcn_mfma_f32_16x16x32_bf16(a[SL][3].v, bb[SL].v, acc[3], 0, 0, 0); \
  } while (0)

  const int J = (iters > kh) ? ((iters - kh + 1) >> 1) : 0;
  if (J > 0) {
    LOAD_FRAGS(0, 0);
    if (J > 1) LOAD_FRAGS(1, 1);
    int j = 0;
    while (true) {
      if (j + 2 < J) LOAD_FRAGS(j + 2, 2);
      MFMA4(0);
      if (++j >= J) break;
      if (j + 2 < J) LOAD_FRAGS(j + 2, 0);
      MFMA4(1);
      if (++j >= J) break;
      if (j + 2 < J) LOAD_FRAGS(j + 2, 1);
      MFMA4(2);
      if (++j >= J) break;
    }
  }
#undef LOAD_FRAGS
#undef MFMA4

  if (kh == 1) {
    float (*rd)[64] = nsub ? red2 : red;
#pragma unroll
    for (int mt = 0; mt < 4; ++mt)
#pragma unroll
      for (int r = 0; r < 4; ++r) rd[mt * 4 + r][lane] = acc[mt][r];
  }
  __syncthreads();
  if (kh == 0) {
    float (*rd)[64] = nsub ? red2 : red;
#pragma unroll
    for (int mt = 0; mt < 4; ++mt)
#pragma unroll
      for (int r = 0; r < 4; ++r) acc[mt][r] += rd[mt * 4 + r][lane];

    const float sinv = 1.0f / S[nbase + lm];
#pragma unroll
    for (int mt = 0; mt < 4; ++mt) {
#pragma unroll
      for (int r = 0; r < 4; ++r) {
        const int c = mt * 16 + quad * 4 + r;
        P[((size_t)(b * 64 + c)) * LSEQ + nbase + lm] = __expf(acc[mt][r] * sinv);
      }
    }
  }
}

__global__ __launch_bounds__(256) void k_scanemit(const int* __restrict__ idx,
                                                  const float* __restrict__ P,
                                                  const float* __restrict__ Wv,
                                                  float* __restrict__ out) {
  __shared__ float Hs[NC][65];
  __shared__ float bins[4][64];
  const int bc = blockIdx.x;
  const int b = bc >> 6;
  const int c = bc & 63;
  const int w = threadIdx.x >> 6;
  const int lane = threadIdx.x & 63;

  const float* __restrict__ prow = P + (size_t)bc * LSEQ;
  const int* __restrict__ irow = idx + b * LSEQ;

  float p[8]; int ii[8];
#pragma unroll
  for (int r = 0; r < 8; ++r) {
    const int ch = w * 8 + r;
    p[r] = prow[ch * 64 + lane];
    ii[r] = irow[ch * 64 + lane];
  }
  for (int i = threadIdx.x; i < NC * 65; i += 256) ((float*)Hs)[i] = 0.f;
  __syncthreads();
#pragma unroll
  for (int r = 0; r < 8; ++r) atomicAdd(&Hs[w * 8 + r][ii[r]], p[r]);
  __syncthreads();

  const int half = lane >> 5, l32 = lane & 31;
#pragma unroll
  for (int r = 0; r < 8; ++r) {
    const int v = w * 16 + r * 2 + half;
    const float h = Hs[l32][v];
    float x = h;
#pragma unroll
    for (int d = 1; d < 32; d <<= 1) {
      float up = __shfl_up(x, d, 32);
      if (l32 >= d) x += up;
    }
    Hs[l32][v] = x - h;
  }
  __syncthreads();

  const float wv = Wv[0];
#pragma unroll
  for (int r = 0; r < 8; ++r) {
    const int ch = w * 8 + r;
    unsigned long long m = __ballot(ii[r] == c);
    while (m) {
      const int srel = __builtin_ctzll(m);
      m &= m - 1;
      const int t = ch * 64 + srel;
      const float pm = (lane <= srel) ? p[r] : 0.f;
      bins[w][lane] = 0.f;
      __threadfence_block();
      atomicAdd(&bins[w][ii[r]], pm);
      __threadfence_block();
      const float bin = bins[w][lane] + Hs[ch][lane];
      float z = bin;
#pragma unroll
      for (int d = 1; d < 64; d <<= 1) z += __shfl_xor(z, d);
      out[((size_t)(b * LSEQ + t)) * 64 + lane] = wv * bin / z;
    }
  }
}

extern "C" void kernel_launch(void* const* d_in, const int* in_sizes, int n_in,
                              void* d_out, int out_size, void* d_ws, size_t ws_size,
                              hipStream_t stream) {
  const int* idx     = (const int*)d_in[0];     // [16, 2048]
  const float* Wq    = (const float*)d_in[1];   // [64, 64]
  const float* Wv    = (const float*)d_in[2];   // [64, 64] (only [0,0] used)
  const float* v_emb = (const float*)d_in[3];   // [2048, 1]
  float* out = (float*)d_out;                   // [16, 2048, 64] fp32

  // workspace: S[2048] f32 | P[1024*2048] f32 | Ebf[2048] bf16 | Agr[16*256*64*8] bf16
  // barrier region at +16MB: cnt1 | cnt2 | flags1[512*32] | flags2[512*32]
  float* S = (float*)d_ws;
  float* P = S + LSEQ;
  unsigned short* Ebf = (unsigned short*)(P + (size_t)NB * NV * LSEQ);
  unsigned short* Agr = Ebf + LSEQ;
  unsigned int* bar = (unsigned int*)((char*)d_ws + (16u << 20));

  // zero counters + both flag arrays: 4096 + 2*64KB
  hipMemsetAsync(bar, 0, 4096 + 2 * 65536, stream);

  const int* a_idx = idx; const float* a_Wq = Wq; const float* a_Wv = Wv;
  const float* a_vemb = v_emb;
  unsigned short* a_Agr = Agr; unsigned short* a_Ebf = Ebf;
  float* a_S = S; float* a_P = P; float* a_out = out;
  unsigned int* a_bar = bar;
  void* args[] = {(void*)&a_idx, (void*)&a_Wq, (void*)&a_Wv, (void*)&a_vemb,
                  (void*)&a_Agr, (void*)&a_Ebf, (void*)&a_S, (void*)&a_P,
                  (void*)&a_out, (void*)&a_bar};

  hipError_t cerr = hipLaunchCooperativeKernel((void*)k_fused, dim3(NBLK),
                                               dim3(256), args, 0, stream);
  if (cerr != hipSuccess) {
    (void)hipGetLastError();   // clear sticky error, fall back to 3-kernel path
    k_gather<<<NB * 16, 256, 0, stream>>>(idx, Wq, v_emb, Agr, Ebf, S);
    k_gemm<<<dim3(64, NB), 256, 0, stream>>>(Agr, Ebf, S, P);
    k_scanemit<<<NB * NV, 256, 0, stream>>>(idx, P, Wv, out);
  }
}